// Round 1
// baseline (143.867 us; speedup 1.0000x reference)
//
#include <hip/hip_runtime.h>
#include <stdint.h>
#include <stddef.h>

// ---------------- types ----------------
typedef __bf16 bf16_t;
typedef bf16_t bf16x4v __attribute__((ext_vector_type(4)));
typedef bf16_t bf16x8v __attribute__((ext_vector_type(8)));
typedef float  f32x4   __attribute__((ext_vector_type(4)));

#define NBATCH 8
#define SEQ    2048
#define DIM    512
#define SP     2052   // padded seq (mult of 12)
#define NL     512    // output rows per batch (SEQ/4)

static __device__ __forceinline__ f32x4 ldbf4(const bf16_t* p) {
  bf16x4v v = *(const bf16x4v*)p;
  f32x4 r;
  r.x = (float)v[0]; r.y = (float)v[1]; r.z = (float)v[2]; r.w = (float)v[3];
  return r;
}
static __device__ __forceinline__ void stbf4(bf16_t* p, f32x4 v) {
  bf16x4v o;
  o[0] = (bf16_t)v.x; o[1] = (bf16_t)v.y; o[2] = (bf16_t)v.z; o[3] = (bf16_t)v.w;
  *(bf16x4v*)p = o;
}

static __device__ __forceinline__ void gload_lds16(const void* g, void* l) {
  __builtin_amdgcn_global_load_lds(
      (const __attribute__((address_space(1))) void*)g,
      (__attribute__((address_space(3))) void*)l, 16, 0, 0);
}

// ---------------- kA: fused Wt transpose + mask normalize + depthwise A --
#define GA_WT   256                        // 16x16 tiles of 32x32
#define GA_MASK 65                         // ceil(8*2052 / 256)
#define GA_A    (NBATCH * SEQ / 2)         // 8192 blocks, 2 rows each
__global__ __launch_bounds__(256) void kA_prep(
    const float* __restrict__ pw, bf16_t* __restrict__ Wt,
    const void* __restrict__ mraw, float* __restrict__ mask01,
    const int* __restrict__ x, const float* __restrict__ emb,
    const float* __restrict__ dww, const float* __restrict__ dwb,
    bf16_t* __restrict__ A) {
  const int bx = blockIdx.x, t = threadIdx.x;
  if (bx < GA_WT) {
    // LDS-tiled transpose: pw (K,N) f32 -> Wt (N,K) bf16, 32x32 tiles
    __shared__ float T[32][33];
    int ti = bx >> 4, tj = bx & 15;        // tile k-row, tile n-col
    int r = t >> 3, c0 = (t & 7) * 4;
    f32x4 v = *(const f32x4*)(pw + (size_t)(ti * 32 + r) * DIM + tj * 32 + c0);
    T[c0 + 0][r] = v.x; T[c0 + 1][r] = v.y;
    T[c0 + 2][r] = v.z; T[c0 + 3][r] = v.w;
    __syncthreads();
    bf16x4v o;
    o[0] = (bf16_t)T[r][c0 + 0]; o[1] = (bf16_t)T[r][c0 + 1];
    o[2] = (bf16_t)T[r][c0 + 2]; o[3] = (bf16_t)T[r][c0 + 3];
    *(bf16x4v*)(Wt + (size_t)(tj * 32 + r) * DIM + ti * 32 + c0) = o;
    return;
  }
  if (bx < GA_WT + GA_MASK) {
    int idx = (bx - GA_WT) * 256 + t;
    if (idx >= NBATCH * SP) return;
    int b = idx / SP, s = idx - b * SP;
    const unsigned char* mb = (const unsigned char*)mraw;
    int u8 = 0;
#pragma unroll
    for (int i = 0; i < 64; i++)
      if ((i & 3) != 0 && mb[i] != 0) u8 = 1;
    float v = 0.f;
    if (s < SEQ) {
      int mi = b * SEQ + s;
      int nz = u8 ? (mb[mi] != 0) : (((const int*)mraw)[mi] != 0);
      v = nz ? 1.f : 0.f;
    }
    mask01[idx] = v;
    return;
  }
  // depthwise conv: 2 rows per block
  int rp = bx - (GA_WT + GA_MASK);
  int row = rp * 2 + (t >> 7);             // 0..16383
  int b = row >> 11, s = row & 2047;
  int d0 = (t & 127) * 4;
  f32x4 acc = *(const f32x4*)(dwb + d0);
#pragma unroll
  for (int tt = 0; tt < 4; tt++) {
    int sp = s + tt;
    if (sp < SEQ) {
      int v = x[b * SEQ + sp];
      f32x4 e = *(const f32x4*)(emb + (size_t)v * DIM + d0);
      f32x4 w = *(const f32x4*)(dww + tt * DIM + d0);
      acc += e * w;
    }
  }
  stbf4(A + (size_t)row * DIM + d0, acc);
}

// ---------------- k2: H = A @ Wt^T + pw_b  (bf16 MFMA) ------------------
#define BM 64
#define BN 128
#define BK 32
__global__ __launch_bounds__(256) void k2_gemm(
    const bf16_t* __restrict__ A, const bf16_t* __restrict__ Bt,
    const float* __restrict__ bias, bf16_t* __restrict__ H) {
  __shared__ __align__(16) bf16_t As[BM * BK];   // 4 KB
  __shared__ __align__(16) bf16_t Bs[BN * BK];   // 8 KB
  const int t = threadIdx.x;
  // XCD swizzle: keep the 4 n-blocks of each m-tile adjacent on one XCD.
  const int bid = blockIdx.x;
  const int xcd = bid & 7, loc = bid >> 3;       // loc 0..127
  const int mt = xcd * 32 + (loc >> 2);          // 0..255
  const int nt = loc & 3;                        // 0..3
  const int m0 = mt * BM, n0 = nt * BN;
  const int lane = t & 63, wave = t >> 6;
  const int wm = (wave & 1) * 32, wn = (wave >> 1) * 64;
  const int mloc = lane & 15, quad = lane >> 4;

  f32x4 acc[2][4] = {};

  char* asd  = (char*)As + t * 16;
  char* bsd1 = (char*)Bs + t * 16;
  char* bsd2 = (char*)Bs + (t + 256) * 16;
  const int ar = t >> 2,           ak = (t & 3) * 8;           // A seg
  const int br1 = t >> 2,          bk1 = (t & 3) * 8;          // B seg 1
  const int br2 = (t + 256) >> 2,  bk2 = (t & 3) * 8;          // B seg 2

  for (int k0 = 0; k0 < 512; k0 += BK) {
    gload_lds16(A + (size_t)(m0 + ar) * DIM + k0 + ak, asd);
    gload_lds16(Bt + (size_t)(n0 + br1) * DIM + k0 + bk1, bsd1);
    gload_lds16(Bt + (size_t)(n0 + br2) * DIM + k0 + bk2, bsd2);
    __syncthreads();
    bf16x8v af[2], bfr[4];
#pragma unroll
    for (int i = 0; i < 2; i++)
      af[i] = *(const bf16x8v*)&As[(wm + i * 16 + mloc) * BK + quad * 8];
#pragma unroll
    for (int i = 0; i < 4; i++)
      bfr[i] = *(const bf16x8v*)&Bs[(wn + i * 16 + mloc) * BK + quad * 8];
#pragma unroll
    for (int mi = 0; mi < 2; mi++)
#pragma unroll
      for (int ni = 0; ni < 4; ni++)
        acc[mi][ni] = __builtin_amdgcn_mfma_f32_16x16x32_bf16(
            af[mi], bfr[ni], acc[mi][ni], 0, 0, 0);
    __syncthreads();
  }
#pragma unroll
  for (int ni = 0; ni < 4; ni++) {
    int col = n0 + wn + ni * 16 + mloc;
    float bv = bias[col];
#pragma unroll
    for (int mi = 0; mi < 2; mi++) {
      int rbase = m0 + wm + mi * 16 + quad * 4;
#pragma unroll
      for (int r = 0; r < 4; r++)
        H[(size_t)(rbase + r) * DIM + col] = (bf16_t)(acc[mi][ni][r] + bv);
    }
  }
}

// ---------------- kB_p: block scores + P softmax (no R materialization) --
__global__ __launch_bounds__(128) void kB_p(
    const bf16_t* __restrict__ H, const float* __restrict__ mask01,
    const float* __restrict__ sw, const float* __restrict__ sbp,
    float* __restrict__ P) {
  const int b = blockIdx.x, c = blockIdx.y;   // c: 0..170
  const int s0 = c * 12;
  const int t = threadIdx.x;
  const int d0 = t * 4;
  const float sb = sbp[0];

  float ms[12], p[12];
  f32x4 swv = *(const f32x4*)(sw + d0);
#pragma unroll
  for (int i = 0; i < 12; i++) {
    int s = s0 + i;
    ms[i] = mask01[b * SP + s];
    if (s < SEQ) {
      f32x4 h = ldbf4(H + ((size_t)b * SEQ + s) * DIM + d0);
      p[i] = h.x * swv.x + h.y * swv.y + h.z * swv.z + h.w * swv.w;
    } else {
      p[i] = 0.f;
    }
  }
#pragma unroll
  for (int off = 32; off > 0; off >>= 1)
#pragma unroll
    for (int i = 0; i < 12; i++) p[i] += __shfl_down(p[i], off);
  __shared__ float hsw[2][12];
  int lane = t & 63, wv = t >> 6;
  if (lane == 0)
#pragma unroll
    for (int i = 0; i < 12; i++) hsw[wv][i] = p[i];
  __syncthreads();
#define HSUM(i) (hsw[0][i] + hsw[1][i])
  if (t < 12) {
    int i = t;
    float m1 = ms[i];
    float v1 = HSUM(i) * m1 + sb;
    int i2 = i & ~1;
    float cc2 = ms[i2] + ms[i2 + 1];
    float s2 = HSUM(i2) * ms[i2] + HSUM(i2 + 1) * ms[i2 + 1];
    float v2 = (cc2 > 0.f ? s2 / cc2 : 0.f) + sb;
    int i3 = (i >= 9) ? 9 : (i >= 6) ? 6 : (i >= 3) ? 3 : 0;
    float cc3 = ms[i3] + ms[i3 + 1] + ms[i3 + 2];
    float s3 = HSUM(i3) * ms[i3] + HSUM(i3 + 1) * ms[i3 + 1] +
               HSUM(i3 + 2) * ms[i3 + 2];
    float v3 = (cc3 > 0.f ? s3 / cc3 : 0.f) + sb;
    int i4 = i & ~3;
    float cc4 = ms[i4] + ms[i4 + 1] + ms[i4 + 2] + ms[i4 + 3];
    float s4 = HSUM(i4) * ms[i4] + HSUM(i4 + 1) * ms[i4 + 1] +
               HSUM(i4 + 2) * ms[i4 + 2] + HSUM(i4 + 3) * ms[i4 + 3];
    float v4 = (cc4 > 0.f ? s4 / cc4 : 0.f) + sb;
    const float NEG = -3.0e38f;
    float a1 = m1 > 0.f ? v1 : NEG, a2 = cc2 > 0.f ? v2 : NEG;
    float a3 = cc3 > 0.f ? v3 : NEG, a4 = cc4 > 0.f ? v4 : NEG;
    float mx = fmaxf(fmaxf(a1, a2), fmaxf(a3, a4));
    f32x4 o;
    if (mx <= NEG) {
      o.x = o.y = o.z = o.w = 0.25f;
    } else {
      float e1 = m1 > 0.f ? __expf(v1 - mx) : 0.f;
      float e2 = cc2 > 0.f ? __expf(v2 - mx) : 0.f;
      float e3 = cc3 > 0.f ? __expf(v3 - mx) : 0.f;
      float e4 = cc4 > 0.f ? __expf(v4 - mx) : 0.f;
      float inv = 1.f / (e1 + e2 + e3 + e4);
      o.x = e1 * inv; o.y = e2 * inv; o.z = e3 * inv; o.w = e4 * inv;
    }
    *(f32x4*)(P + ((size_t)b * SP + s0 + i) * 4) = o;
  }
#undef HSUM
}

// ---------------- k56: fused seq attention + on-the-fly level means ------
// Each block: batch b, 16 consecutive s-rows (4 output l's). Stages the
// whole per-batch P (2052 x f32x4 = 32.8 KB LDS, L2-resident source),
// computes attention weights for its 16 rows (16 j-chunks/row), then
// recomputes the R2/R3/R4 means from an 8-row H halo in registers and
// writes the chunk-mean output. Eliminates R2/R3/R4 + Wacc entirely.
#define KS  16     // s-rows per block
#define KJL 129    // ceil(SP/16) j-chunk length
__global__ __launch_bounds__(256) void k56_out(
    const bf16_t* __restrict__ H, const float* __restrict__ P,
    const float* __restrict__ mask01, float* __restrict__ out,
    float* __restrict__ omask) {
  const int b = blockIdx.x, yb = blockIdx.y;   // yb 0..127
  const int t = threadIdx.x;
  const int S0 = yb * KS;
  __shared__ f32x4 Q[SP];          // 32832 B
  __shared__ f32x4 wsh[KS];
  __shared__ float msh[KS + 8];    // rows S0-2 .. S0+21
  __shared__ float red[4];

  // stage P (zero masked cols, count them) + mask halo
  float cnt0 = 0.f;
  for (int j = t; j < SP; j += 256) {
    f32x4 q = *(const f32x4*)(P + ((size_t)b * SP + j) * 4);
    if (mask01[b * SP + j] == 0.f) {
      q.x = q.y = q.z = q.w = 0.f;
      cnt0 += 1.f;
    }
    Q[j] = q;
  }
  if (t < KS + 8) {
    int s = S0 - 2 + t;
    msh[t] = (s >= 0 && s < SP) ? mask01[b * SP + s] : 0.f;
  }
#pragma unroll
  for (int off = 32; off > 0; off >>= 1) cnt0 += __shfl_down(cnt0, off);
  if ((t & 63) == 0) red[t >> 6] = cnt0;
  __syncthreads();
  const float nmask = red[0] + red[1] + red[2] + red[3];

  // attention: row il = t>>4 (0..15), j-chunk jc = t&15
  {
    const int il = t >> 4, jc = t & 15;
    const f32x4 qi = Q[S0 + il];
    int j0 = jc * KJL, j1 = j0 + KJL;
    if (j1 > SP) j1 = SP;
    f32x4 acc; acc.x = acc.y = acc.z = acc.w = 0.f;
    float den = 0.f;
    for (int j = j0; j < j1; j++) {
      f32x4 pj = Q[j];
      float sim = qi.x * pj.x + qi.y * pj.y + qi.z * pj.z + qi.w * pj.w;
      float e = __expf(sim);
      den += e;
      acc += e * pj;
    }
#pragma unroll
    for (int off = 8; off > 0; off >>= 1) {
      acc.x += __shfl_down(acc.x, off); acc.y += __shfl_down(acc.y, off);
      acc.z += __shfl_down(acc.z, off); acc.w += __shfl_down(acc.w, off);
      den += __shfl_down(den, off);
    }
    if (jc == 0) {
      den -= nmask;                       // remove exp(qi.0)=1 of masked j
      float inv = den > 0.f ? 1.f / den : 0.f;
      f32x4 w;
      w.x = acc.x * inv; w.y = acc.y * inv;
      w.z = acc.z * inv; w.w = acc.w * inv;
      wsh[il] = w;
    }
  }
  __syncthreads();

  // combine: slot = it*256+t -> ll = slot>>7 (0..3), d0 = (slot&127)*4
#pragma unroll
  for (int it = 0; it < 2; it++) {
    const int slot = it * 256 + t;
    const int ll = slot >> 7;            // wave-uniform
    const int d0 = (slot & 127) * 4;
    const int sb = ll * 4;               // local s base; msh offset +2
    f32x4 h[8]; float mk[8];
#pragma unroll
    for (int k = 0; k < 8; k++) {
      mk[k] = msh[sb + k];
      int sg = S0 + sb - 2 + k;
      sg = sg < 0 ? 0 : (sg > SEQ - 1 ? SEQ - 1 : sg);
      h[k] = ldbf4(H + ((size_t)b * SEQ + sg) * DIM + d0);
    }
    float c4 = mk[2] + mk[3] + mk[4] + mk[5];
    float i4 = c4 > 0.f ? 1.f / c4 : 0.f;
    f32x4 r4 = (h[2] * mk[2] + h[3] * mk[3] + h[4] * mk[4] + h[5] * mk[5]) * i4;
    float c2a = mk[2] + mk[3], c2b = mk[4] + mk[5];
    f32x4 r2a = (h[2] * mk[2] + h[3] * mk[3]) * (c2a > 0.f ? 1.f / c2a : 0.f);
    f32x4 r2b = (h[4] * mk[4] + h[5] * mk[5]) * (c2b > 0.f ? 1.f / c2b : 0.f);
    const f32x4 w0 = wsh[sb], w1 = wsh[sb + 1];
    const f32x4 w2 = wsh[sb + 2], w3 = wsh[sb + 3];
#define MEAN3(K)                                                         \
    ((h[K] * mk[K] + h[(K) + 1] * mk[(K) + 1] + h[(K) + 2] * mk[(K) + 2]) * \
     ((mk[K] + mk[(K) + 1] + mk[(K) + 2]) > 0.f                          \
          ? 1.f / (mk[K] + mk[(K) + 1] + mk[(K) + 2]) : 0.f))
    f32x4 o;
    const int r = (S0 + sb) % 3;         // wave-uniform branch
    if (r == 0) {
      f32x4 A = MEAN3(2), B = MEAN3(5);
      o = mk[2] * (w0.x * h[2] + w0.y * r2a + w0.z * A + w0.w * r4)
        + mk[3] * (w1.x * h[3] + w1.y * r2a + w1.z * A + w1.w * r4)
        + mk[4] * (w2.x * h[4] + w2.y * r2b + w2.z * A + w2.w * r4)
        + mk[5] * (w3.x * h[5] + w3.y * r2b + w3.z * B + w3.w * r4);
    } else if (r == 1) {
      f32x4 A = MEAN3(1), B = MEAN3(4);
      o = mk[2] * (w0.x * h[2] + w0.y * r2a + w0.z * A + w0.w * r4)
        + mk[3] * (w1.x * h[3] + w1.y * r2a + w1.z * A + w1.w * r4)
        + mk[4] * (w2.x * h[4] + w2.y * r2b + w2.z * B + w2.w * r4)
        + mk[5] * (w3.x * h[5] + w3.y * r2b + w3.z * B + w3.w * r4);
    } else {
      f32x4 A = MEAN3(0), B = MEAN3(3);
      o = mk[2] * (w0.x * h[2] + w0.y * r2a + w0.z * A + w0.w * r4)
        + mk[3] * (w1.x * h[3] + w1.y * r2a + w1.z * B + w1.w * r4)
        + mk[4] * (w2.x * h[4] + w2.y * r2b + w2.z * B + w2.w * r4)
        + mk[5] * (w3.x * h[5] + w3.y * r2b + w3.z * B + w3.w * r4);
    }
#undef MEAN3
    o *= i4;                             // final DS=4 chunk mean
    const int l = yb * 4 + ll;
    *(f32x4*)(out + ((size_t)b * NL + l) * DIM + d0) = o;
    if (d0 == 0) omask[b * NL + l] = c4 > 0.f ? 1.f : 0.f;
  }
}

// ---------------- launch ----------------
extern "C" void kernel_launch(void* const* d_in, const int* in_sizes, int n_in,
                              void* d_out, int out_size, void* d_ws, size_t ws_size,
                              hipStream_t stream) {
  const int*   x    = (const int*)d_in[0];
  const void*  mraw = d_in[1];
  const float* emb  = (const float*)d_in[2];
  const float* dww  = (const float*)d_in[3];
  const float* dwb  = (const float*)d_in[4];
  const float* pw   = (const float*)d_in[5];
  const float* pwb  = (const float*)d_in[6];
  const float* sw   = (const float*)d_in[7];
  const float* sb   = (const float*)d_in[8];

  char* ws = (char*)d_ws;
  size_t off = 0;
  auto alloc = [&](size_t bytes) {
    size_t o = off;
    off = (off + bytes + 255) & ~(size_t)255;
    return o;
  };
  bf16_t* A     = (bf16_t*)(ws + alloc((size_t)NBATCH * SEQ * DIM * 2));
  bf16_t* H     = (bf16_t*)(ws + alloc((size_t)NBATCH * SEQ * DIM * 2));
  bf16_t* Wt    = (bf16_t*)(ws + alloc((size_t)DIM * DIM * 2));
  float* mask01 = (float*)(ws + alloc((size_t)NBATCH * SP * 4));
  float* P      = (float*)(ws + alloc((size_t)NBATCH * SP * 4 * 4));

  float* out   = (float*)d_out;
  float* omask = out + (size_t)NBATCH * NL * DIM;

  kA_prep<<<GA_WT + GA_MASK + GA_A, 256, 0, stream>>>(pw, Wt, mraw, mask01,
                                                      x, emb, dww, dwb, A);
  k2_gemm<<<1024, 256, 0, stream>>>(A, Wt, pwb, H);
  kB_p<<<dim3(NBATCH, 171), 128, 0, stream>>>(H, mask01, sw, sb, P);
  k56_out<<<dim3(NBATCH, 128), 256, 0, stream>>>(H, P, mask01, out, omask);
}

// Round 2
// 131.596 us; speedup vs baseline: 1.0932x; 1.0932x over previous
//
#include <hip/hip_runtime.h>
#include <stdint.h>
#include <stddef.h>

// ---------------- types ----------------
typedef __bf16 bf16_t;
typedef bf16_t bf16x4v __attribute__((ext_vector_type(4)));
typedef bf16_t bf16x8v __attribute__((ext_vector_type(8)));
typedef float  f32x4   __attribute__((ext_vector_type(4)));

#define NBATCH 8
#define SEQ    2048
#define DIM    512
#define SP     2052   // padded seq (mult of 12)
#define NL     512    // output rows per batch (SEQ/4)
#define MROWS  1088   // 4*256 token rows + 1 bias row + 63 pad rows

static __device__ __forceinline__ f32x4 ldbf4(const bf16_t* p) {
  bf16x4v v = *(const bf16x4v*)p;
  f32x4 r;
  r.x = (float)v[0]; r.y = (float)v[1]; r.z = (float)v[2]; r.w = (float)v[3];
  return r;
}
static __device__ __forceinline__ void stbf4(bf16_t* p, f32x4 v) {
  bf16x4v o;
  o[0] = (bf16_t)v.x; o[1] = (bf16_t)v.y; o[2] = (bf16_t)v.z; o[3] = (bf16_t)v.w;
  *(bf16x4v*)p = o;
}

static __device__ __forceinline__ void gload_lds16(const void* g, void* l) {
  __builtin_amdgcn_global_load_lds(
      (const __attribute__((address_space(1))) void*)g,
      (__attribute__((address_space(3))) void*)l, 16, 0, 0);
}

// ---------------- kP: Wt transpose + mask normalize + Atilde build ------
// Atilde rows: r = tt*256 + v  -> bf16(emb[v,:] * dww[tt,:])   (r < 1024)
//              r = 1024        -> bf16(dwb[:])                  (bias row)
//              r = 1025..1087  -> 0                             (tile pad)
#define GP_WT   256                        // 16x16 tiles of 32x32
#define GP_MASK 65                         // ceil(8*2052 / 256)
#define GP_SC   544                        // 1088*512/4 elems / 256 thr
__global__ __launch_bounds__(256) void kP_prep(
    const float* __restrict__ pw, bf16_t* __restrict__ Wt,
    const void* __restrict__ mraw, float* __restrict__ mask01,
    const float* __restrict__ emb, const float* __restrict__ dww,
    const float* __restrict__ dwb, bf16_t* __restrict__ At) {
  const int bx = blockIdx.x, t = threadIdx.x;
  if (bx < GP_WT) {
    // LDS-tiled transpose: pw (K,N) f32 -> Wt (N,K) bf16, 32x32 tiles
    __shared__ float T[32][33];
    int ti = bx >> 4, tj = bx & 15;        // tile k-row, tile n-col
    int r = t >> 3, c0 = (t & 7) * 4;
    f32x4 v = *(const f32x4*)(pw + (size_t)(ti * 32 + r) * DIM + tj * 32 + c0);
    T[c0 + 0][r] = v.x; T[c0 + 1][r] = v.y;
    T[c0 + 2][r] = v.z; T[c0 + 3][r] = v.w;
    __syncthreads();
    bf16x4v o;
    o[0] = (bf16_t)T[r][c0 + 0]; o[1] = (bf16_t)T[r][c0 + 1];
    o[2] = (bf16_t)T[r][c0 + 2]; o[3] = (bf16_t)T[r][c0 + 3];
    *(bf16x4v*)(Wt + (size_t)(tj * 32 + r) * DIM + ti * 32 + c0) = o;
    return;
  }
  if (bx < GP_WT + GP_MASK) {
    int idx = (bx - GP_WT) * 256 + t;
    if (idx >= NBATCH * SP) return;
    int b = idx / SP, s = idx - b * SP;
    const unsigned char* mb = (const unsigned char*)mraw;
    int u8 = 0;
#pragma unroll
    for (int i = 0; i < 64; i++)
      if ((i & 3) != 0 && mb[i] != 0) u8 = 1;
    float v = 0.f;
    if (s < SEQ) {
      int mi = b * SEQ + s;
      int nz = u8 ? (mb[mi] != 0) : (((const int*)mraw)[mi] != 0);
      v = nz ? 1.f : 0.f;
    }
    mask01[idx] = v;
    return;
  }
  // Atilde build
  int idx = (bx - (GP_WT + GP_MASK)) * 256 + t;   // 0..139263
  int r = idx >> 7, d0 = (idx & 127) * 4;
  f32x4 o4;
  if (r < 1024) {
    int tt = r >> 8, v = r & 255;
    f32x4 e = *(const f32x4*)(emb + (size_t)v * DIM + d0);
    f32x4 w = *(const f32x4*)(dww + tt * DIM + d0);
    o4 = e * w;
  } else if (r == 1024) {
    o4 = *(const f32x4*)(dwb + d0);
  } else {
    o4.x = o4.y = o4.z = o4.w = 0.f;
  }
  stbf4(At + (size_t)r * DIM + d0, o4);
}

// ---------------- kM: M = Atilde @ Wt^T  (1088x512x512, f32 out) --------
#define BM 64
#define BN 128
#define BK 32
__global__ __launch_bounds__(256) void kM_gemm(
    const bf16_t* __restrict__ A, const bf16_t* __restrict__ Bt,
    float* __restrict__ M) {
  __shared__ __align__(16) bf16_t As[BM * BK];   // 4 KB
  __shared__ __align__(16) bf16_t Bs[BN * BK];   // 8 KB
  const int t = threadIdx.x;
  const int mt = blockIdx.x >> 2;                // 0..16
  const int nt = blockIdx.x & 3;                 // 0..3
  const int m0 = mt * BM, n0 = nt * BN;
  const int lane = t & 63, wave = t >> 6;
  const int wm = (wave & 1) * 32, wn = (wave >> 1) * 64;
  const int mloc = lane & 15, quad = lane >> 4;

  f32x4 acc[2][4] = {};

  char* asd  = (char*)As + t * 16;
  char* bsd1 = (char*)Bs + t * 16;
  char* bsd2 = (char*)Bs + (t + 256) * 16;
  const int ar = t >> 2,           ak = (t & 3) * 8;
  const int br1 = t >> 2,          bk1 = (t & 3) * 8;
  const int br2 = (t + 256) >> 2,  bk2 = (t & 3) * 8;

  for (int k0 = 0; k0 < 512; k0 += BK) {
    gload_lds16(A + (size_t)(m0 + ar) * DIM + k0 + ak, asd);
    gload_lds16(Bt + (size_t)(n0 + br1) * DIM + k0 + bk1, bsd1);
    gload_lds16(Bt + (size_t)(n0 + br2) * DIM + k0 + bk2, bsd2);
    __syncthreads();
    bf16x8v af[2], bfr[4];
#pragma unroll
    for (int i = 0; i < 2; i++)
      af[i] = *(const bf16x8v*)&As[(wm + i * 16 + mloc) * BK + quad * 8];
#pragma unroll
    for (int i = 0; i < 4; i++)
      bfr[i] = *(const bf16x8v*)&Bs[(wn + i * 16 + mloc) * BK + quad * 8];
#pragma unroll
    for (int mi = 0; mi < 2; mi++)
#pragma unroll
      for (int ni = 0; ni < 4; ni++)
        acc[mi][ni] = __builtin_amdgcn_mfma_f32_16x16x32_bf16(
            af[mi], bfr[ni], acc[mi][ni], 0, 0, 0);
    __syncthreads();
  }
#pragma unroll
  for (int ni = 0; ni < 4; ni++) {
    int col = n0 + wn + ni * 16 + mloc;
#pragma unroll
    for (int mi = 0; mi < 2; mi++) {
      int rbase = m0 + wm + mi * 16 + quad * 4;
#pragma unroll
      for (int r = 0; r < 4; r++)
        M[(size_t)(rbase + r) * DIM + col] = acc[mi][ni][r];
    }
  }
}

// ---------------- kB: H + P from token-table gathers ---------------------
// H[s,:] = M[x[s]] + M[256+x[s+1]] + M[512+x[s+2]] + M[768+x[s+3]]
//          + M[1024] + pwb     (terms with s+tt >= SEQ skipped)
__global__ __launch_bounds__(128) void kB_hp(
    const float* __restrict__ Mt, const int* __restrict__ x,
    const float* __restrict__ pwb, const float* __restrict__ mask01,
    const float* __restrict__ sw, const float* __restrict__ sbp,
    bf16_t* __restrict__ H, float* __restrict__ P) {
  const int b = blockIdx.x, c = blockIdx.y;   // c: 0..170
  const int s0 = c * 12;
  const int t = threadIdx.x;
  const int d0 = t * 4;
  const float sb = sbp[0];

  f32x4 swv = *(const f32x4*)(sw + d0);
  f32x4 bias2 = *(const f32x4*)(Mt + (size_t)1024 * DIM + d0)
              + *(const f32x4*)(pwb + d0);
  float ms[12], p[12];
#pragma unroll
  for (int i = 0; i < 12; i++) {
    int s = s0 + i;
    ms[i] = mask01[b * SP + s];
    if (s < SEQ) {
      f32x4 h = bias2;
      int base = b * SEQ + s;
#pragma unroll
      for (int tt = 0; tt < 4; tt++) {
        if (s + tt < SEQ) {
          int v = x[base + tt];
          h += *(const f32x4*)(Mt + (size_t)((tt << 8) + v) * DIM + d0);
        }
      }
      p[i] = h.x * swv.x + h.y * swv.y + h.z * swv.z + h.w * swv.w;
      stbf4(H + ((size_t)b * SEQ + s) * DIM + d0, h);
    } else {
      p[i] = 0.f;
    }
  }
#pragma unroll
  for (int off = 32; off > 0; off >>= 1)
#pragma unroll
    for (int i = 0; i < 12; i++) p[i] += __shfl_down(p[i], off);
  __shared__ float hsw[2][12];
  int lane = t & 63, wv = t >> 6;
  if (lane == 0)
#pragma unroll
    for (int i = 0; i < 12; i++) hsw[wv][i] = p[i];
  __syncthreads();
#define HSUM(i) (hsw[0][i] + hsw[1][i])
  if (t < 12) {
    int i = t;
    float m1 = ms[i];
    float v1 = HSUM(i) * m1 + sb;
    int i2 = i & ~1;
    float cc2 = ms[i2] + ms[i2 + 1];
    float s2 = HSUM(i2) * ms[i2] + HSUM(i2 + 1) * ms[i2 + 1];
    float v2 = (cc2 > 0.f ? s2 / cc2 : 0.f) + sb;
    int i3 = (i >= 9) ? 9 : (i >= 6) ? 6 : (i >= 3) ? 3 : 0;
    float cc3 = ms[i3] + ms[i3 + 1] + ms[i3 + 2];
    float s3 = HSUM(i3) * ms[i3] + HSUM(i3 + 1) * ms[i3 + 1] +
               HSUM(i3 + 2) * ms[i3 + 2];
    float v3 = (cc3 > 0.f ? s3 / cc3 : 0.f) + sb;
    int i4 = i & ~3;
    float cc4 = ms[i4] + ms[i4 + 1] + ms[i4 + 2] + ms[i4 + 3];
    float s4 = HSUM(i4) * ms[i4] + HSUM(i4 + 1) * ms[i4 + 1] +
               HSUM(i4 + 2) * ms[i4 + 2] + HSUM(i4 + 3) * ms[i4 + 3];
    float v4 = (cc4 > 0.f ? s4 / cc4 : 0.f) + sb;
    const float NEG = -3.0e38f;
    float a1 = m1 > 0.f ? v1 : NEG, a2 = cc2 > 0.f ? v2 : NEG;
    float a3 = cc3 > 0.f ? v3 : NEG, a4 = cc4 > 0.f ? v4 : NEG;
    float mx = fmaxf(fmaxf(a1, a2), fmaxf(a3, a4));
    f32x4 o;
    if (mx <= NEG) {
      o.x = o.y = o.z = o.w = 0.25f;
    } else {
      float e1 = m1 > 0.f ? __expf(v1 - mx) : 0.f;
      float e2 = cc2 > 0.f ? __expf(v2 - mx) : 0.f;
      float e3 = cc3 > 0.f ? __expf(v3 - mx) : 0.f;
      float e4 = cc4 > 0.f ? __expf(v4 - mx) : 0.f;
      float inv = 1.f / (e1 + e2 + e3 + e4);
      o.x = e1 * inv; o.y = e2 * inv; o.z = e3 * inv; o.w = e4 * inv;
    }
    *(f32x4*)(P + ((size_t)b * SP + s0 + i) * 4) = o;
  }
#undef HSUM
}

// ---------------- k56: fused seq attention + on-the-fly level means ------
#define KS  16     // s-rows per block
#define KJL 129    // ceil(SP/16) j-chunk length
__global__ __launch_bounds__(256) void k56_out(
    const bf16_t* __restrict__ H, const float* __restrict__ P,
    const float* __restrict__ mask01, float* __restrict__ out,
    float* __restrict__ omask) {
  const int b = blockIdx.x, yb = blockIdx.y;   // yb 0..127
  const int t = threadIdx.x;
  const int S0 = yb * KS;
  __shared__ f32x4 Q[SP];          // 32832 B
  __shared__ f32x4 wsh[KS];
  __shared__ float msh[KS + 8];    // rows S0-2 .. S0+21
  __shared__ float red[4];

  // stage P (zero masked cols, count them) + mask halo
  float cnt0 = 0.f;
  for (int j = t; j < SP; j += 256) {
    f32x4 q = *(const f32x4*)(P + ((size_t)b * SP + j) * 4);
    if (mask01[b * SP + j] == 0.f) {
      q.x = q.y = q.z = q.w = 0.f;
      cnt0 += 1.f;
    }
    Q[j] = q;
  }
  if (t < KS + 8) {
    int s = S0 - 2 + t;
    msh[t] = (s >= 0 && s < SP) ? mask01[b * SP + s] : 0.f;
  }
#pragma unroll
  for (int off = 32; off > 0; off >>= 1) cnt0 += __shfl_down(cnt0, off);
  if ((t & 63) == 0) red[t >> 6] = cnt0;
  __syncthreads();
  const float nmask = red[0] + red[1] + red[2] + red[3];

  // attention: row il = t>>4 (0..15), j-chunk jc = t&15
  {
    const int il = t >> 4, jc = t & 15;
    const f32x4 qi = Q[S0 + il];
    int j0 = jc * KJL, j1 = j0 + KJL;
    if (j1 > SP) j1 = SP;
    f32x4 acc; acc.x = acc.y = acc.z = acc.w = 0.f;
    float den = 0.f;
    for (int j = j0; j < j1; j++) {
      f32x4 pj = Q[j];
      float sim = qi.x * pj.x + qi.y * pj.y + qi.z * pj.z + qi.w * pj.w;
      float e = __expf(sim);
      den += e;
      acc += e * pj;
    }
#pragma unroll
    for (int off = 8; off > 0; off >>= 1) {
      acc.x += __shfl_down(acc.x, off); acc.y += __shfl_down(acc.y, off);
      acc.z += __shfl_down(acc.z, off); acc.w += __shfl_down(acc.w, off);
      den += __shfl_down(den, off);
    }
    if (jc == 0) {
      den -= nmask;                       // remove exp(qi.0)=1 of masked j
      float inv = den > 0.f ? 1.f / den : 0.f;
      f32x4 w;
      w.x = acc.x * inv; w.y = acc.y * inv;
      w.z = acc.z * inv; w.w = acc.w * inv;
      wsh[il] = w;
    }
  }
  __syncthreads();

  // combine: slot = it*256+t -> ll = slot>>7 (0..3), d0 = (slot&127)*4
#pragma unroll
  for (int it = 0; it < 2; it++) {
    const int slot = it * 256 + t;
    const int ll = slot >> 7;            // wave-uniform
    const int d0 = (slot & 127) * 4;
    const int sb = ll * 4;               // local s base; msh offset +2
    f32x4 h[8]; float mk[8];
#pragma unroll
    for (int k = 0; k < 8; k++) {
      mk[k] = msh[sb + k];
      int sg = S0 + sb - 2 + k;
      sg = sg < 0 ? 0 : (sg > SEQ - 1 ? SEQ - 1 : sg);
      h[k] = ldbf4(H + ((size_t)b * SEQ + sg) * DIM + d0);
    }
    float c4 = mk[2] + mk[3] + mk[4] + mk[5];
    float i4 = c4 > 0.f ? 1.f / c4 : 0.f;
    f32x4 r4 = (h[2] * mk[2] + h[3] * mk[3] + h[4] * mk[4] + h[5] * mk[5]) * i4;
    float c2a = mk[2] + mk[3], c2b = mk[4] + mk[5];
    f32x4 r2a = (h[2] * mk[2] + h[3] * mk[3]) * (c2a > 0.f ? 1.f / c2a : 0.f);
    f32x4 r2b = (h[4] * mk[4] + h[5] * mk[5]) * (c2b > 0.f ? 1.f / c2b : 0.f);
    const f32x4 w0 = wsh[sb], w1 = wsh[sb + 1];
    const f32x4 w2 = wsh[sb + 2], w3 = wsh[sb + 3];
#define MEAN3(K)                                                         \
    ((h[K] * mk[K] + h[(K) + 1] * mk[(K) + 1] + h[(K) + 2] * mk[(K) + 2]) * \
     ((mk[K] + mk[(K) + 1] + mk[(K) + 2]) > 0.f                          \
          ? 1.f / (mk[K] + mk[(K) + 1] + mk[(K) + 2]) : 0.f))
    f32x4 o;
    const int r = (S0 + sb) % 3;         // wave-uniform branch
    if (r == 0) {
      f32x4 A = MEAN3(2), B = MEAN3(5);
      o = mk[2] * (w0.x * h[2] + w0.y * r2a + w0.z * A + w0.w * r4)
        + mk[3] * (w1.x * h[3] + w1.y * r2a + w1.z * A + w1.w * r4)
        + mk[4] * (w2.x * h[4] + w2.y * r2b + w2.z * A + w2.w * r4)
        + mk[5] * (w3.x * h[5] + w3.y * r2b + w3.z * B + w3.w * r4);
    } else if (r == 1) {
      f32x4 A = MEAN3(1), B = MEAN3(4);
      o = mk[2] * (w0.x * h[2] + w0.y * r2a + w0.z * A + w0.w * r4)
        + mk[3] * (w1.x * h[3] + w1.y * r2a + w1.z * A + w1.w * r4)
        + mk[4] * (w2.x * h[4] + w2.y * r2b + w2.z * B + w2.w * r4)
        + mk[5] * (w3.x * h[5] + w3.y * r2b + w3.z * B + w3.w * r4);
    } else {
      f32x4 A = MEAN3(0), B = MEAN3(3);
      o = mk[2] * (w0.x * h[2] + w0.y * r2a + w0.z * A + w0.w * r4)
        + mk[3] * (w1.x * h[3] + w1.y * r2a + w1.z * B + w1.w * r4)
        + mk[4] * (w2.x * h[4] + w2.y * r2b + w2.z * B + w2.w * r4)
        + mk[5] * (w3.x * h[5] + w3.y * r2b + w3.z * B + w3.w * r4);
    }
#undef MEAN3
    o *= i4;                             // final DS=4 chunk mean
    const int l = yb * 4 + ll;
    *(f32x4*)(out + ((size_t)b * NL + l) * DIM + d0) = o;
    if (d0 == 0) omask[b * NL + l] = c4 > 0.f ? 1.f : 0.f;
  }
}

// ---------------- launch ----------------
extern "C" void kernel_launch(void* const* d_in, const int* in_sizes, int n_in,
                              void* d_out, int out_size, void* d_ws, size_t ws_size,
                              hipStream_t stream) {
  const int*   x    = (const int*)d_in[0];
  const void*  mraw = d_in[1];
  const float* emb  = (const float*)d_in[2];
  const float* dww  = (const float*)d_in[3];
  const float* dwb  = (const float*)d_in[4];
  const float* pw   = (const float*)d_in[5];
  const float* pwb  = (const float*)d_in[6];
  const float* sw   = (const float*)d_in[7];
  const float* sb   = (const float*)d_in[8];

  char* ws = (char*)d_ws;
  size_t off = 0;
  auto alloc = [&](size_t bytes) {
    size_t o = off;
    off = (off + bytes + 255) & ~(size_t)255;
    return o;
  };
  bf16_t* H     = (bf16_t*)(ws + alloc((size_t)NBATCH * SEQ * DIM * 2));
  bf16_t* Wt    = (bf16_t*)(ws + alloc((size_t)DIM * DIM * 2));
  bf16_t* At    = (bf16_t*)(ws + alloc((size_t)MROWS * DIM * 2));
  float*  Mt    = (float*)(ws + alloc((size_t)MROWS * DIM * 4));
  float* mask01 = (float*)(ws + alloc((size_t)NBATCH * SP * 4));
  float* P      = (float*)(ws + alloc((size_t)NBATCH * SP * 4 * 4));

  float* out   = (float*)d_out;
  float* omask = out + (size_t)NBATCH * NL * DIM;

  kP_prep<<<GP_WT + GP_MASK + GP_SC, 256, 0, stream>>>(pw, Wt, mraw, mask01,
                                                       emb, dww, dwb, At);
  kM_gemm<<<68, 256, 0, stream>>>(At, Wt, Mt);
  kB_hp<<<dim3(NBATCH, 171), 128, 0, stream>>>(Mt, x, pwb, mask01, sw, sb,
                                               H, P);
  k56_out<<<dim3(NBATCH, 128), 256, 0, stream>>>(H, P, mask01, out, omask);
}